// Round 5
// baseline (79.103 us; speedup 1.0000x reference)
//
#include <hip/hip_runtime.h>
#include <math.h>

#define WBLOCK 64              // one wave per block: zero barriers
#define FPCW   256             // frames per chunk (per wave)
#define F4_ROT 576             // FPCW*9/4 float4 per rot array per chunk (9 per lane)
#define F4_POSE 192            // FPCW*3/4 float4 per pose array per chunk (3 per lane)
#define MAXGRID 768            // 3 blocks/CU x 256 CU, all-resident

#define GLOAD_LDS16(gp, lp)                                                     \
  __builtin_amdgcn_global_load_lds(                                             \
      (const __attribute__((address_space(1))) void*)(gp),                      \
      (__attribute__((address_space(3))) void*)(lp), 16, 0, 0)

__global__ __launch_bounds__(WBLOCK) void rmse_partial_kernel(
    const float* __restrict__ rot_kf, const float* __restrict__ pose_kf,
    const float* __restrict__ rot_gt, const float* __restrict__ pose_gt,
    float* __restrict__ partial, int N)
{
    // wave-private double-buffered slices; 49152 B total -> 3 blocks/CU
    __shared__ float4 ldsA[2][F4_ROT];
    __shared__ float4 ldsB[2][F4_ROT];
    __shared__ float4 ldsPK[2][F4_POSE];
    __shared__ float4 ldsPG[2][F4_POSE];

    const int lane = threadIdx.x;
    const long long rotF4max  = ((long long)N * 9 >= 4) ? ((long long)N * 9 - 4) / 4 : 0;
    const long long poseF4max = ((long long)N * 3 >= 4) ? ((long long)N * 3 - 4) / 4 : 0;
    const int nChunks = (int)(((long long)N + FPCW - 1) / FPCW);
    const int stride = gridDim.x;

    // issue one chunk's 24 loads (18 rot + 6 pose), all via global_load_lds
    auto issueAll = [&](int cc, int par) {
        const long long rb = (long long)cc * F4_ROT;
        #pragma unroll
        for (int j = 0; j < 9; ++j) {
            long long f4 = rb + j * WBLOCK + lane;
            if (f4 > rotF4max) f4 = rotF4max;
            GLOAD_LDS16(reinterpret_cast<const float4*>(rot_kf) + f4,
                        (void*)&ldsA[par][j * WBLOCK + lane]);
        }
        #pragma unroll
        for (int j = 0; j < 9; ++j) {
            long long f4 = rb + j * WBLOCK + lane;
            if (f4 > rotF4max) f4 = rotF4max;
            GLOAD_LDS16(reinterpret_cast<const float4*>(rot_gt) + f4,
                        (void*)&ldsB[par][j * WBLOCK + lane]);
        }
        const long long pb = (long long)cc * F4_POSE;
        #pragma unroll
        for (int j = 0; j < 3; ++j) {
            long long f4 = pb + j * WBLOCK + lane;
            if (f4 > poseF4max) f4 = poseF4max;
            GLOAD_LDS16(reinterpret_cast<const float4*>(pose_kf) + f4,
                        (void*)&ldsPK[par][j * WBLOCK + lane]);
        }
        #pragma unroll
        for (int j = 0; j < 3; ++j) {
            long long f4 = pb + j * WBLOCK + lane;
            if (f4 > poseF4max) f4 = poseF4max;
            GLOAD_LDS16(reinterpret_cast<const float4*>(pose_gt) + f4,
                        (void*)&ldsPG[par][j * WBLOCK + lane]);
        }
    };

    float sum = 0.0f;
    int c = blockIdx.x;
    int par = 0;

    if (c < nChunks) issueAll(c, 0);

    while (c < nChunks) {
        const int cn = c + stride;
        const bool hasNext = (cn < nChunks);

        // depth-2 prefetch into the other slice set (its reads finished last iter)
        if (hasNext) issueAll(cn, par ^ 1);

        // wait only for THIS chunk's 24 loads; next chunk's 24 stay in flight
        if (hasNext) { asm volatile("s_waitcnt vmcnt(24)" ::: "memory"); }
        else         { asm volatile("s_waitcnt vmcnt(0)"  ::: "memory"); }
        __builtin_amdgcn_sched_barrier(0);

        // lane owns 4 consecutive frames: floats [lane*36, +36) of the chunk
        float4 ta[9], tb[9], tk[3], tg[3];
        #pragma unroll
        for (int j = 0; j < 9; ++j) ta[j] = ldsA[par][lane * 9 + j];
        #pragma unroll
        for (int j = 0; j < 9; ++j) tb[j] = ldsB[par][lane * 9 + j];
        #pragma unroll
        for (int j = 0; j < 3; ++j) tk[j] = ldsPK[par][lane * 3 + j];
        #pragma unroll
        for (int j = 0; j < 3; ++j) tg[j] = ldsPG[par][lane * 3 + j];

        float af[36], bf[36], kf[12], gf[12];
        #pragma unroll
        for (int j = 0; j < 9; ++j) {
            af[4*j] = ta[j].x; af[4*j+1] = ta[j].y; af[4*j+2] = ta[j].z; af[4*j+3] = ta[j].w;
            bf[4*j] = tb[j].x; bf[4*j+1] = tb[j].y; bf[4*j+2] = tb[j].z; bf[4*j+3] = tb[j].w;
        }
        #pragma unroll
        for (int j = 0; j < 3; ++j) {
            kf[4*j] = tk[j].x; kf[4*j+1] = tk[j].y; kf[4*j+2] = tk[j].z; kf[4*j+3] = tk[j].w;
            gf[4*j] = tg[j].x; gf[4*j+1] = tg[j].y; gf[4*j+2] = tg[j].z; gf[4*j+3] = tg[j].w;
        }

        const int fbase = c * FPCW + lane * 4;
        #pragma unroll
        for (int s = 0; s < 4; ++s) {
            if (fbase + s < N) {
                const float* a = &af[s * 9];
                const float* b = &bf[s * 9];
                const float d0 = gf[s*3+0] - kf[s*3+0];
                const float d1 = gf[s*3+1] - kf[s*3+1];
                const float d2 = gf[s*3+2] - kf[s*3+2];
                float se = 0.0f;
                #pragma unroll
                for (int i = 0; i < 3; ++i) {
                    #pragma unroll
                    for (int k = 0; k < 3; ++k) {
                        // R_rel[i][k] = sum_j A[j][i]*B[j][k]
                        float r = a[i] * b[k] + a[3+i] * b[3+k] + a[6+i] * b[6+k];
                        r -= (i == k) ? 1.0f : 0.0f;
                        se += r * r;
                    }
                    const float t = a[i] * d0 + a[3+i] * d1 + a[6+i] * d2;
                    se += t * t;
                }
                sum += se;
            }
        }

        // all my ds_reads retired before next iteration overwrites this slice set
        asm volatile("s_waitcnt lgkmcnt(0)" ::: "memory");
        __builtin_amdgcn_sched_barrier(0);

        c = cn;
        par ^= 1;
    }

    // single-wave reduction, no barrier needed
    #pragma unroll
    for (int off = 32; off > 0; off >>= 1) sum += __shfl_down(sum, off);
    if (lane == 0) partial[blockIdx.x] = sum;
}

__global__ __launch_bounds__(256) void rmse_finalize_kernel(
    const float* __restrict__ partial, int nPartial, float* __restrict__ out, int N)
{
    __shared__ float redbuf[4];
    float sum = 0.0f;
    for (int i = threadIdx.x; i < nPartial; i += 256) sum += partial[i];
    #pragma unroll
    for (int off = 32; off > 0; off >>= 1) sum += __shfl_down(sum, off);
    const int lane = threadIdx.x & 63;
    const int wave = threadIdx.x >> 6;
    if (lane == 0) redbuf[wave] = sum;
    __syncthreads();
    if (threadIdx.x == 0) {
        float s = redbuf[0] + redbuf[1] + redbuf[2] + redbuf[3];
        out[0] = sqrtf(s / (float)N) + 1e-8f;
    }
}

extern "C" void kernel_launch(void* const* d_in, const int* in_sizes, int n_in,
                              void* d_out, int out_size, void* d_ws, size_t ws_size,
                              hipStream_t stream) {
    const float* rot_kf  = (const float*)d_in[0];
    const float* pose_kf = (const float*)d_in[1];
    const float* rot_gt  = (const float*)d_in[2];
    const float* pose_gt = (const float*)d_in[3];
    float* out = (float*)d_out;
    float* partial = (float*)d_ws;

    const int N = in_sizes[1] / 3;   // pose_kf is [N,3]
    const int nChunks = (int)(((long long)N + FPCW - 1) / FPCW);

    int grid = MAXGRID;
    if (grid > nChunks) grid = nChunks;
    const int wsCap = (int)(ws_size / sizeof(float));
    if (grid > wsCap) grid = wsCap;
    if (grid < 1) grid = 1;

    rmse_partial_kernel<<<grid, WBLOCK, 0, stream>>>(rot_kf, pose_kf, rot_gt, pose_gt, partial, N);
    rmse_finalize_kernel<<<1, 256, 0, stream>>>(partial, grid, out, N);
}